// Round 1
// baseline (125.221 us; speedup 1.0000x reference)
//
#include <hip/hip_runtime.h>

// KPN per-pixel 5x5 predicted convolution, channels-last fp32.
// out[b,h,w,c] = sum_{i,j} feat[b,h+i-2,w+j-2,c] * kernel[b,h,w,i*5+j] + bias[c]
//
// Layout: 256-thread blocks, each thread = one (pixel, 4-channel group).
//   cg = (t&7)*4, pixel = p0 + (t>>3)  -> flat float4 index = p0*32 + t*4
//   => perfectly coalesced float4 loads/stores (1 KiB per wave instruction).
// Kernel weights (32 pixels x 25 taps = 3.2 KB) staged in LDS; readback is
// an 8-lane broadcast per address, stride-25 across pixels -> conflict-free.

#define BB 4
#define HH 256
#define WW 256
#define CC 32
#define KK 5
#define PADR 2
#define PPB 32   // pixels per block
#define TPB 256  // threads per block

__global__ __launch_bounds__(TPB) void kpn_conv_kernel(
    const float* __restrict__ feat,
    const float* __restrict__ kern,
    const float* __restrict__ bias,
    float* __restrict__ out)
{
    __shared__ float sk[PPB * KK * KK];  // 800 floats = 3.2 KB

    const int t  = threadIdx.x;
    const int p0 = blockIdx.x * PPB;

    // Stage this block's kernel weights (contiguous in global) into LDS.
    const float* kbase = kern + (size_t)p0 * (KK * KK);
    for (int idx = t; idx < PPB * KK * KK; idx += TPB) {
        sk[idx] = kbase[idx];
    }
    __syncthreads();

    const int pixLocal = t >> 3;       // 0..31
    const int cg       = (t & 7) * 4;  // channel group start: 0,4,...,28
    const int p  = p0 + pixLocal;      // flat pixel index in [0, B*H*W)
    const int b  = p >> 16;            // H*W = 65536
    const int hw = p & 65535;
    const int h  = hw >> 8;            // W = 256
    const int w  = hw & 255;

    float4 acc = *(const float4*)(bias + cg);

    const float* fb  = feat + (((size_t)b) << 16) * CC;  // batch base
    const float* skp = sk + pixLocal * (KK * KK);

    #pragma unroll
    for (int i = 0; i < KK; ++i) {
        const int hh = h + i - PADR;
        const bool hv = (unsigned)hh < (unsigned)HH;
        #pragma unroll
        for (int j = 0; j < KK; ++j) {
            const int ww = w + j - PADR;
            const float wgt = skp[i * KK + j];
            if (hv && (unsigned)ww < (unsigned)WW) {
                const float4 f =
                    *(const float4*)(fb + ((((size_t)hh << 8) + ww) << 5) + cg);
                acc.x += f.x * wgt;
                acc.y += f.y * wgt;
                acc.z += f.z * wgt;
                acc.w += f.w * wgt;
            }
        }
    }

    *(float4*)(out + (((size_t)p) << 5) + cg) = acc;
}

extern "C" void kernel_launch(void* const* d_in, const int* in_sizes, int n_in,
                              void* d_out, int out_size, void* d_ws, size_t ws_size,
                              hipStream_t stream) {
    const float* feat = (const float*)d_in[0];
    const float* kern = (const float*)d_in[1];
    const float* bias = (const float*)d_in[2];
    float* out = (float*)d_out;

    const int nPix = BB * HH * WW;          // 262144
    dim3 grid(nPix / PPB);                  // 8192 blocks
    dim3 block(TPB);
    kpn_conv_kernel<<<grid, block, 0, stream>>>(feat, kern, bias, out);
}

// Round 2
// 117.233 us; speedup vs baseline: 1.0681x; 1.0681x over previous
//
#include <hip/hip_runtime.h>

// KPN per-pixel 5x5 predicted convolution, channels-last fp32.
// out[b,h,w,c] = sum_{i,j} feat[b,h+i-2,w+j-2,c] * kernel[b,h,w,i*5+j] + bias[c]
//
// Round 2: latency-bound fix.
//  - Each thread computes VH=4 vertically-adjacent outputs for one (w, cg=4ch)
//    slot -> feat rows shared across outputs: 8 row-loads x 5 cols = 40 float4
//    loads per 4 outputs (10/output vs 25/output in round 1).
//  - All feat loads are UNCONDITIONAL (clamped w, uniform row-validity branch),
//    fully unrolled -> compiler keeps many loads in flight (round 1's per-tap
//    divergent branches forced serial vmcnt(0) waits; VGPR_Count was 12).
//  - Per-pixel weights staged in LDS [oh][w][25]; 8 cg-lanes broadcast, 8
//    w-lanes hit banks 25*w mod 32 = all distinct -> conflict-free.

#define BB 4
#define HH 256
#define WW 256
#define CC 32
#define KK 5
#define VH 4    // output rows per thread
#define TW 32   // tile width (pixels)
#define TPB 256

__global__ __launch_bounds__(TPB) void kpn_conv_kernel(
    const float* __restrict__ feat,
    const float* __restrict__ kern,
    const float* __restrict__ bias,
    float* __restrict__ out)
{
    __shared__ float sk[VH * TW * KK * KK];  // 3200 floats = 12.8 KB

    const int t = threadIdx.x;

    // Block decode: grid = B * (H/VH) * (W/TW) = 4 * 64 * 8 = 2048 blocks.
    const int bw = blockIdx.x & 7;          // W/TW = 8
    const int bh = (blockIdx.x >> 3) & 63;  // H/VH = 64
    const int b  = blockIdx.x >> 9;         // B = 4
    const int h0 = bh * VH;
    const int w0 = bw * TW;

    // ---- Stage tile weights into LDS (4 rows x 800 contiguous floats each).
    // Global chunk per row is 3200-byte aligned (w0 % 32 == 0 -> pix0*100B).
    const float* kb = kern + ((size_t)((b * HH + h0) * WW + w0)) * (KK * KK);
    #pragma unroll
    for (int it = 0; it < 4; ++it) {  // 800 float4s, 256 threads -> 4 rounds
        int idx = t + it * TPB;
        if (idx < VH * TW * KK * KK / 4) {
            int row = idx / 200;            // 200 float4 per h-row
            int off = (idx - row * 200) * 4;
            *(float4*)(sk + row * (TW * KK * KK) + off) =
                *(const float4*)(kb + (size_t)row * WW * KK * KK + off);
        }
    }
    __syncthreads();

    const int cg = (t & 7) * 4;   // channel group start
    const int wL = t >> 3;        // 0..31
    const int w  = w0 + wL;

    const float4 bz = *(const float4*)(bias + cg);
    float4 acc[VH];
    #pragma unroll
    for (int oh = 0; oh < VH; ++oh) acc[oh] = bz;

    const float* fb = feat + (((size_t)b) << 16) * CC;  // batch base

    #pragma unroll
    for (int r = 0; r < VH + KK - 1; ++r) {  // feat rows h0-2 .. h0+5
        const int hh = h0 + r - (KK / 2);
        if ((unsigned)hh < (unsigned)HH) {   // wave-uniform branch
            // Load the 5-wide window for this row, unconditional, clamped.
            float4 f[KK];
            #pragma unroll
            for (int j = 0; j < KK; ++j) {
                int ww  = w + j - (KK / 2);
                int wwc = min(max(ww, 0), WW - 1);
                f[j] = *(const float4*)(fb + ((((size_t)hh << 8) + wwc) << 5) + cg);
            }
            // Zero OOB columns (cndmask, no branch).
            #pragma unroll
            for (int j = 0; j < KK; ++j) {
                int ww = w + j - (KK / 2);
                if ((unsigned)ww >= (unsigned)WW) {
                    f[j].x = 0.f; f[j].y = 0.f; f[j].z = 0.f; f[j].w = 0.f;
                }
            }
            // Accumulate into every output row that uses feat row r.
            #pragma unroll
            for (int oh = 0; oh < VH; ++oh) {
                const int ii = r - oh;               // kernel row index
                if (ii >= 0 && ii < KK) {            // compile-time after unroll
                    const float* wp = sk + oh * (TW * KK * KK) + wL * (KK * KK) + ii * KK;
                    #pragma unroll
                    for (int j = 0; j < KK; ++j) {
                        const float wg = wp[j];
                        acc[oh].x += f[j].x * wg;
                        acc[oh].y += f[j].y * wg;
                        acc[oh].z += f[j].z * wg;
                        acc[oh].w += f[j].w * wg;
                    }
                }
            }
        }
    }

    // ---- Store VH coalesced rows.
    #pragma unroll
    for (int oh = 0; oh < VH; ++oh) {
        const size_t pix = (size_t)(b * HH + h0 + oh) * WW + w;
        *(float4*)(out + pix * CC + cg) = acc[oh];
    }
}

extern "C" void kernel_launch(void* const* d_in, const int* in_sizes, int n_in,
                              void* d_out, int out_size, void* d_ws, size_t ws_size,
                              hipStream_t stream) {
    const float* feat = (const float*)d_in[0];
    const float* kern = (const float*)d_in[1];
    const float* bias = (const float*)d_in[2];
    float* out = (float*)d_out;

    dim3 grid(BB * (HH / VH) * (WW / TW));  // 2048 blocks
    dim3 block(TPB);
    kpn_conv_kernel<<<grid, block, 0, stream>>>(feat, kern, bias, out);
}